// Round 1
// baseline (430.786 us; speedup 1.0000x reference)
//
#include <hip/hip_runtime.h>

#define DEV __device__ __forceinline__

typedef float f32x4 __attribute__((ext_vector_type(4)));
typedef short s16x4 __attribute__((ext_vector_type(4)));
typedef short s16x8 __attribute__((ext_vector_type(8)));

DEV float bf2f(short s) {
  unsigned u = ((unsigned)(unsigned short)s) << 16;
  return __builtin_bit_cast(float, u);
}
DEV short f2bf(float f) {
  unsigned u = __builtin_bit_cast(unsigned, f);
  u += 0x7FFFu + ((u >> 16) & 1u);   // RNE
  return (short)(u >> 16);
}

DEV void gld_lds16(const void* g, void* l) {
  __builtin_amdgcn_global_load_lds(
      (const __attribute__((address_space(1))) void*)g,
      (__attribute__((address_space(3))) void*)l, 16, 0, 0);
}

// ---------------- fused front-end: conv + W^T builds + histograms ----------------
// blocks [0,4096): f32->bf16 conversion (grid-stride over nconv elems)
// blocks [4096,4352): W0T build; [4352,4608): W1T build
// blocks [4608,5120): hist of ed0; [5120,5184): hist of ed1
__global__ void prep_k(const float* __restrict__ feat, short* __restrict__ fbf, long nconv,
                       const float* __restrict__ Ws0, const float* __restrict__ Wn0,
                       short* __restrict__ W0T,
                       const float* __restrict__ Ws1, const float* __restrict__ Wn1,
                       short* __restrict__ W1T,
                       const int* __restrict__ ed0, int E0, int* __restrict__ deg0,
                       const int* __restrict__ ed1, int E1, int* __restrict__ deg1) {
  const int b = blockIdx.x, tid = threadIdx.x;
  if (b < 4096) {
    long i = ((long)b * 256 + tid) * 4;
    const long stride = (long)4096 * 256 * 4;
    for (; i < nconv; i += stride) {
      f32x4 v = *(const f32x4*)(feat + i);
      s16x4 o;
      o[0] = f2bf(v[0]); o[1] = f2bf(v[1]); o[2] = f2bf(v[2]); o[3] = f2bf(v[3]);
      *(s16x4*)(fbf + i) = o;
    }
  } else if (b < 4608) {
    const bool first = b < 4352;
    const float* Ws = first ? Ws0 : Ws1;
    const float* Wn = first ? Wn0 : Wn1;
    short* WT = first ? W0T : W1T;
    const int N = first ? 512 : 256, KH = first ? 256 : 512;
    const int K = KH * 2;
    const int lb = b - (first ? 4096 : 4352);
    for (int idx = lb * 256 + tid; idx < N * K; idx += 256 * 256) {
      int n = idx / K, k = idx - n * K;
      float v = (k < KH) ? Ws[(size_t)k * N + n] : Wn[(size_t)(k - KH) * N + n];
      WT[idx] = f2bf(v);
    }
  } else if (b < 5120) {
    const int lb = b - 4608;
    for (int e = lb * 256 + tid; e < E0; e += 512 * 256) atomicAdd(&deg0[ed0[e]], 1);
  } else {
    const int lb = b - 5120;
    for (int e = lb * 256 + tid; e < E1; e += 64 * 256) atomicAdd(&deg1[ed1[e]], 1);
  }
}

// ---------------- both scans in one launch: block 0 -> layer0, block 1 -> layer1 ----------------
// writes exclusive prefix into off[] AND cur[] (cur doubles as the fill cursor; no memset needed)
__global__ __launch_bounds__(1024) void scan2_k(const int* __restrict__ d0, int* __restrict__ o0,
                                                int* __restrict__ c0, int n0,
                                                const int* __restrict__ d1, int* __restrict__ o1,
                                                int* __restrict__ c1, int n1) {
  const int* cnt; int* off; int* cur; int n;
  if (blockIdx.x == 0) { cnt = d0; off = o0; cur = c0; n = n0; }
  else                 { cnt = d1; off = o1; cur = c1; n = n1; }
  __shared__ int sh[1024];
  int t = threadIdx.x;
  int per = (n + 1023) >> 10;
  int s0 = t * per, s1 = min(s0 + per, n);
  int s = 0;
  for (int i = s0; i < s1; ++i) s += cnt[i];
  sh[t] = s;
  __syncthreads();
  for (int d = 1; d < 1024; d <<= 1) {
    int u = (t >= d) ? sh[t - d] : 0;
    __syncthreads();
    sh[t] += u;
    __syncthreads();
  }
  int run = sh[t] - s;  // exclusive prefix over thread chunks
  for (int i = s0; i < s1; ++i) { off[i] = run; cur[i] = run; run += cnt[i]; }
}

// ---------------- both fills in one launch; cur holds absolute offsets ----------------
__global__ void fill2_k(const int* __restrict__ es0, const int* __restrict__ ed0, int E0,
                        int* __restrict__ cur0, int* __restrict__ bk0,
                        const int* __restrict__ es1, const int* __restrict__ ed1, int E1,
                        int* __restrict__ cur1, int* __restrict__ bk1) {
  const int b = blockIdx.x, tid = threadIdx.x;
  if (b < 896) {
    for (int e = b * 256 + tid; e < E0; e += 896 * 256) {
      int d = ed0[e];
      int p = atomicAdd(&cur0[d], 1);
      bk0[p] = es0[e];
    }
  } else {
    const int lb = b - 896;
    for (int e = lb * 256 + tid; e < E1; e += 64 * 256) {
      int d = ed1[e];
      int p = atomicAdd(&cur1[d], 1);
      bk1[p] = es1[e];
    }
  }
}

// ---------------- mean aggregation: one wave per dst row ----------------
__global__ void agg_f32_256(const float* __restrict__ X, const int* __restrict__ off,
                            const int* __restrict__ deg, const int* __restrict__ bucket,
                            short* __restrict__ out, int n_dst) {
  int gw = (blockIdx.x * blockDim.x + threadIdx.x) >> 6;
  if (gw >= n_dst) return;
  int lane = threadIdx.x & 63;
  int start = off[gw], cnt = deg[gw];
  float a[4] = {0, 0, 0, 0}, b[4] = {0, 0, 0, 0};
  int i = 0;
  for (; i + 2 <= cnt; i += 2) {
    int s0 = bucket[start + i], s1 = bucket[start + i + 1];
    f32x4 v0 = *(const f32x4*)(X + (size_t)s0 * 256 + lane * 4);
    f32x4 v1 = *(const f32x4*)(X + (size_t)s1 * 256 + lane * 4);
#pragma unroll
    for (int j = 0; j < 4; ++j) { a[j] += v0[j]; b[j] += v1[j]; }
  }
  if (i < cnt) {
    int s0 = bucket[start + i];
    f32x4 v0 = *(const f32x4*)(X + (size_t)s0 * 256 + lane * 4);
#pragma unroll
    for (int j = 0; j < 4; ++j) a[j] += v0[j];
  }
  float inv = 1.0f / (float)(cnt > 0 ? cnt : 1);
  s16x4 o;
#pragma unroll
  for (int j = 0; j < 4; ++j) o[j] = f2bf((a[j] + b[j]) * inv);
  *(s16x4*)(out + (size_t)gw * 256 + lane * 4) = o;
}

__global__ void agg_bf16_256(const short* __restrict__ X, const int* __restrict__ off,
                             const int* __restrict__ deg, const int* __restrict__ bucket,
                             short* __restrict__ out, int n_dst) {
  int gw = (blockIdx.x * blockDim.x + threadIdx.x) >> 6;
  if (gw >= n_dst) return;
  int lane = threadIdx.x & 63;
  int start = off[gw], cnt = deg[gw];
  float a[4] = {0, 0, 0, 0}, b[4] = {0, 0, 0, 0};
  int i = 0;
  for (; i + 2 <= cnt; i += 2) {
    int s0 = bucket[start + i], s1 = bucket[start + i + 1];
    s16x4 v0 = *(const s16x4*)(X + (size_t)s0 * 256 + lane * 4);
    s16x4 v1 = *(const s16x4*)(X + (size_t)s1 * 256 + lane * 4);
#pragma unroll
    for (int j = 0; j < 4; ++j) { a[j] += bf2f(v0[j]); b[j] += bf2f(v1[j]); }
  }
  if (i < cnt) {
    int s0 = bucket[start + i];
    s16x4 v0 = *(const s16x4*)(X + (size_t)s0 * 256 + lane * 4);
#pragma unroll
    for (int j = 0; j < 4; ++j) a[j] += bf2f(v0[j]);
  }
  float inv = 1.0f / (float)(cnt > 0 ? cnt : 1);
  s16x4 o;
#pragma unroll
  for (int j = 0; j < 4; ++j) o[j] = f2bf((a[j] + b[j]) * inv);
  *(s16x4*)(out + (size_t)gw * 256 + lane * 4) = o;
}

__global__ void agg_bf16_512(const short* __restrict__ X, const int* __restrict__ off,
                             const int* __restrict__ deg, const int* __restrict__ bucket,
                             short* __restrict__ out, int n_dst) {
  int gw = (blockIdx.x * blockDim.x + threadIdx.x) >> 6;
  if (gw >= n_dst) return;
  int lane = threadIdx.x & 63;
  int start = off[gw], cnt = deg[gw];
  float a[8] = {0, 0, 0, 0, 0, 0, 0, 0}, b[8] = {0, 0, 0, 0, 0, 0, 0, 0};
  int i = 0;
  for (; i + 2 <= cnt; i += 2) {
    int s0 = bucket[start + i], s1 = bucket[start + i + 1];
    s16x8 v0 = *(const s16x8*)(X + (size_t)s0 * 512 + lane * 8);
    s16x8 v1 = *(const s16x8*)(X + (size_t)s1 * 512 + lane * 8);
#pragma unroll
    for (int j = 0; j < 8; ++j) { a[j] += bf2f(v0[j]); b[j] += bf2f(v1[j]); }
  }
  if (i < cnt) {
    int s0 = bucket[start + i];
    s16x8 v0 = *(const s16x8*)(X + (size_t)s0 * 512 + lane * 8);
#pragma unroll
    for (int j = 0; j < 8; ++j) a[j] += bf2f(v0[j]);
  }
  float inv = 1.0f / (float)(cnt > 0 ? cnt : 1);
  s16x8 o;
#pragma unroll
  for (int j = 0; j < 8; ++j) o[j] = f2bf((a[j] + b[j]) * inv);
  *(s16x8*)(out + (size_t)gw * 512 + lane * 8) = o;
}

// ---------------- bf16 MFMA GEMM: C[M,N] = [Aleft|Aright] (M x K, bf16) * Bt^T + bias ----------------
// Bt is N x K row-major (i.e. W^T), bf16. A is split at K/2 across two buffers, each ld = KH.
// BM x 128 tile, BK=64, 4 waves (2x2), wave computes (BM/2)x64 via (BM/32)x4 frags of 16x16x32.
// LDS tiles XOR-swizzled (T2): phys_byte = row*128 + (kb ^ ((row&7)<<4)); staged with
// linear-dest global_load_lds + pre-swizzled global source (rule #21).
template <int BM, bool RELU_BF16>
__global__ __launch_bounds__(256, 2) void gemm_k(
    const short* __restrict__ Aleft, const short* __restrict__ Aright,
    const short* __restrict__ Bt, const float* __restrict__ bias,
    void* __restrict__ Cout, int M, int N, int K, int KH) {
  constexpr int MFR = BM / 32;       // 16-row frags per wave in M
  constexpr int PA = BM / 32;        // 1KB staging chunks per wave for A
  __shared__ short As[BM * 64];
  __shared__ short Bs[128 * 64];
  const int tid = threadIdx.x;
  const int w = tid >> 6, lane = tid & 63;
  const int m0 = blockIdx.y * BM, n0 = blockIdx.x * 128;
  const int wr = w >> 1, wc = w & 1;
  const int lr = lane & 15, lk = (lane >> 4) << 3;

  f32x4 acc[MFR][4] = {};

  const int nkt = K >> 6;
  const int ktH = KH >> 6;
  const size_t ldA = (size_t)KH * 2;  // bytes
  const size_t ldB = (size_t)K * 2;   // bytes

  for (int kt = 0; kt < nkt; ++kt) {
    const char* Abase = (const char*)((kt < ktH) ? Aleft : Aright);
    const int ktl = (kt < ktH) ? kt : kt - ktH;
#pragma unroll
    for (int j = 0; j < PA; ++j) {
      int c = w * PA + j;
      int o = (c << 10) + lane * 16;             // byte offset in A tile
      int row = o >> 7;                          // 128 B per row (BK=64 bf16)
      int kb = o & 127;
      int kbs = kb ^ ((row & 7) << 4);           // pre-swizzled source column
      int ar = m0 + row; if (ar > M - 1) ar = M - 1;
      gld_lds16(Abase + (size_t)ar * ldA + (size_t)(ktl * 128 + kbs),
                ((char*)As) + (c << 10));
    }
#pragma unroll
    for (int j = 0; j < 4; ++j) {
      int c = w * 4 + j;
      int o = (c << 10) + lane * 16;
      int row = o >> 7;
      int kb = o & 127;
      int kbs = kb ^ ((row & 7) << 4);
      gld_lds16((const char*)Bt + (size_t)(n0 + row) * ldB + (size_t)(kt * 128 + kbs),
                ((char*)Bs) + (c << 10));
    }
    __syncthreads();
#pragma unroll
    for (int kk = 0; kk < 2; ++kk) {
      s16x8 af[MFR], bfr[4];
      const int kbyte = (kk * 32 + lk) * 2;
#pragma unroll
      for (int m = 0; m < MFR; ++m) {
        int r = wr * (BM / 2) + m * 16 + lr;
        af[m] = *(const s16x8*)((const char*)As + (r << 7) + (kbyte ^ ((r & 7) << 4)));
      }
#pragma unroll
      for (int n = 0; n < 4; ++n) {
        int r = wc * 64 + n * 16 + lr;
        bfr[n] = *(const s16x8*)((const char*)Bs + (r << 7) + (kbyte ^ ((r & 7) << 4)));
      }
#pragma unroll
      for (int m = 0; m < MFR; ++m)
#pragma unroll
        for (int n = 0; n < 4; ++n)
          acc[m][n] = __builtin_amdgcn_mfma_f32_16x16x32_bf16(af[m], bfr[n], acc[m][n], 0, 0, 0);
    }
    __syncthreads();
  }

  const int rq = (lane >> 4) * 4;
#pragma unroll
  for (int m = 0; m < MFR; ++m) {
#pragma unroll
    for (int n = 0; n < 4; ++n) {
      const int col = n0 + wc * 64 + n * 16 + lr;
      const float bv = bias[col];
#pragma unroll
      for (int j = 0; j < 4; ++j) {
        const int row = m0 + wr * (BM / 2) + m * 16 + rq + j;
        if (row < M) {
          float v = acc[m][n][j] + bv;
          if (RELU_BF16) {
            v = v > 0.0f ? v : 0.0f;
            ((short*)Cout)[(size_t)row * N + col] = f2bf(v);
          } else {
            ((float*)Cout)[(size_t)row * N + col] = v;
          }
        }
      }
    }
  }
}

// ---------------- launcher ----------------
extern "C" void kernel_launch(void* const* d_in, const int* in_sizes, int n_in,
                              void* d_out, int out_size, void* d_ws, size_t ws_size,
                              hipStream_t stream) {
  const int NS0 = 200000, ND0 = 40000, ND1 = 8000;
  const int E0 = 1000000, E1 = 80000;
  const int DIN = 256, DH = 512, DOUT = 256;

  const float* feat = (const float*)d_in[0];
  const float* Wself0 = (const float*)d_in[1];
  const float* Wneigh0 = (const float*)d_in[2];
  const float* b0 = (const float*)d_in[3];
  const float* Wself1 = (const float*)d_in[4];
  const float* Wneigh1 = (const float*)d_in[5];
  const float* b1 = (const float*)d_in[6];
  const int* es0 = (const int*)d_in[7];
  const int* ed0 = (const int*)d_in[8];
  const int* es1 = (const int*)d_in[9];
  const int* ed1 = (const int*)d_in[10];

  char* w = (char*)d_ws;
  size_t pos = 0;
  auto take = [&](size_t b) -> char* {
    char* p = w + pos;
    pos += (b + 255) & ~(size_t)255;
    return p;
  };

  short* hne0 = (short*)take((size_t)ND0 * DIN * 2);
  short* h = (short*)take((size_t)ND0 * DH * 2);
  short* hne1 = (short*)take((size_t)ND1 * DH * 2);
  short* hdst0buf = (short*)take((size_t)ND0 * DIN * 2);
  short* W0T = (short*)take((size_t)DH * 2 * DIN * 2);
  short* W1T = (short*)take((size_t)DOUT * 2 * DH * 2);
  int* deg0 = (int*)take((size_t)ND0 * 4);   // deg0/deg1 adjacent: one memset covers both
  int* deg1 = (int*)take((size_t)ND1 * 4);   // (ND0*4 = 160000 is 256-aligned)
  int* off0 = (int*)take((size_t)ND0 * 4);
  int* cur0 = (int*)take((size_t)ND0 * 4);
  int* bucket0 = (int*)take((size_t)E0 * 4);
  int* off1 = (int*)take((size_t)ND1 * 4);
  int* cur1 = (int*)take((size_t)ND1 * 4);
  int* bucket1 = (int*)take((size_t)E1 * 4);
  short* featbf = (short*)take((size_t)NS0 * DIN * 2);
  const bool use_bf = (ws_size >= pos);
  (void)in_sizes; (void)n_in; (void)out_size;

  // zero both histograms in one shot; cur* is initialized by scan2_k (cur = off)
  hipMemsetAsync(deg0, 0, (size_t)(ND0 + ND1) * 4, stream);

  const short* hdst0 = use_bf ? featbf : hdst0buf;

  // fused front-end: conversion || W^T builds || histograms
  prep_k<<<5184, 256, 0, stream>>>(
      feat, use_bf ? featbf : hdst0buf,
      use_bf ? (long)NS0 * DIN : (long)ND0 * DIN,
      Wself0, Wneigh0, W0T, Wself1, Wneigh1, W1T,
      ed0, E0, deg0, ed1, E1, deg1);

  // both scans in one launch (2 blocks)
  scan2_k<<<2, 1024, 0, stream>>>(deg0, off0, cur0, ND0, deg1, off1, cur1, ND1);

  // both fills in one launch
  fill2_k<<<960, 256, 0, stream>>>(es0, ed0, E0, cur0, bucket0,
                                   es1, ed1, E1, cur1, bucket1);

  if (use_bf)
    agg_bf16_256<<<ND0 / 4, 256, 0, stream>>>(featbf, off0, deg0, bucket0, hne0, ND0);
  else
    agg_f32_256<<<ND0 / 4, 256, 0, stream>>>(feat, off0, deg0, bucket0, hne0, ND0);

  // layer 0 GEMM: (40000 x 512) = [feat[:40000] | hne0] @ [Wself0;Wneigh0], +b0, relu, bf16 out
  gemm_k<128, true><<<dim3(DH / 128, (ND0 + 127) / 128), 256, 0, stream>>>(
      hdst0, hne0, W0T, b0, h, ND0, DH, 2 * DIN, DIN);

  agg_bf16_512<<<ND1 / 4, 256, 0, stream>>>(h, off1, deg1, bucket1, hne1, ND1);

  // layer 1 GEMM: (8000 x 256) = [h[:8000] | hne1] @ [Wself1;Wneigh1], +b1, f32 out
  // BM=64 tile -> grid (2,125)=250 blocks (was 126) to fill the 256 CUs
  gemm_k<64, false><<<dim3(DOUT / 128, (ND1 + 63) / 64), 256, 0, stream>>>(
      h, hne1, W1T, b1, d_out, ND1, DOUT, 2 * DH, DH);
}